// Round 3
// baseline (1591.383 us; speedup 1.0000x reference)
//
#include <hip/hip_runtime.h>

// ---------------- constants for this problem ----------------
#define DH 128          // d_in = d_hidden = 128
#define KTOT 1408       // 8*128 rel + 3*128 root slots
#define LDA 40          // LDS row pitch in bf16 (32 + 8 pad)
#define DOUT2 349
#define DOUT2P 384      // padded to 3 x 128 N-tiles

typedef short v8s __attribute__((ext_vector_type(8)));
typedef float v4f __attribute__((ext_vector_type(4)));

__device__ __forceinline__ unsigned short f2bf(float f) {
  unsigned int u = __float_as_uint(f);
  u += 0x7fffu + ((u >> 16) & 1u);
  return (unsigned short)(u >> 16);
}
__device__ __forceinline__ unsigned int pack2(float a, float b) {
  return (unsigned int)f2bf(a) | ((unsigned int)f2bf(b) << 16);
}

// ------------- int64-vs-int32 detect + normalize -------------
// If node_type is int64, every odd 32-bit word in its first N words is a high
// half of a small nonneg value -> 0. If int32, odd words are node_type values
// (0..2, ~2/3 nonzero over 60k samples). flag!=0 <=> int32.
__global__ void k_detect(const int* __restrict__ nt_raw, int* __restrict__ flag, int half) {
  int i = blockIdx.x * 256 + threadIdx.x;
  if (i >= half) return;
  if (nt_raw[2 * i + 1] != 0) atomicOr(flag, 1);
}
__global__ void k_cvt(const int* __restrict__ in, int* __restrict__ out, int n,
                      const int* __restrict__ flag) {
  int i = blockIdx.x * 256 + threadIdx.x;
  if (i >= n) return;
  out[i] = (*flag) ? in[i] : in[2 * i];  // int64: little-endian low word
}

// ------------- build x [N][128] bf16 from f32 x0/x1/emb2 -------------
__global__ void k_gather(const float4* __restrict__ x0, const float4* __restrict__ x1,
                         const float4* __restrict__ x2, const int* __restrict__ nt,
                         const int* __restrict__ li, ushort4* __restrict__ xout, int total) {
  int i = blockIdx.x * 256 + threadIdx.x;
  if (i >= total) return;              // total = N*32 (32 float4 per 128-f32 row)
  int node = i >> 5, c = i & 31;
  int t = nt[node];
  int l = li[node];
  const float4* s = (t == 0) ? x0 : (t == 1) ? x1 : x2;
  float4 v = s[(size_t)l * 32 + c];
  ushort4 o;
  o.x = f2bf(v.x); o.y = f2bf(v.y); o.z = f2bf(v.z); o.w = f2bf(v.w);
  xout[i] = o;
}

// ------------- histogram over key = dst*8 + edge_type -------------
__global__ void k_count(const int* __restrict__ src_dst, const int* __restrict__ et,
                        int* __restrict__ cnt, int E) {
  int i = blockIdx.x * 256 + threadIdx.x;
  if (i >= E) return;
  int dst = src_dst[E + i];
  int r = et[i];
  atomicAdd(&cnt[dst * 8 + r], 1);
}

// ------------- 3-phase exclusive scan over n = N*8 -------------
__global__ __launch_bounds__(1024) void k_scan1(const int* __restrict__ cnt,
                                                int* __restrict__ outl,
                                                int* __restrict__ bsums, int n) {
  __shared__ int s[1024];
  int tid = threadIdx.x;
  int gid = blockIdx.x * 1024 + tid;
  int v = (gid < n) ? cnt[gid] : 0;
  s[tid] = v;
  __syncthreads();
  for (int o = 1; o < 1024; o <<= 1) {
    int t = (tid >= o) ? s[tid - o] : 0;
    __syncthreads();
    s[tid] += t;
    __syncthreads();
  }
  if (gid < n) outl[gid] = s[tid] - v;  // exclusive, block-local
  if (tid == 1023) bsums[blockIdx.x] = s[1023];
}
__global__ __launch_bounds__(1024) void k_scan2(int* __restrict__ bsums, int nb) {
  __shared__ int s[1024];
  int tid = threadIdx.x;
  int v = (tid < nb) ? bsums[tid] : 0;
  s[tid] = v;
  __syncthreads();
  for (int o = 1; o < 1024; o <<= 1) {
    int t = (tid >= o) ? s[tid - o] : 0;
    __syncthreads();
    s[tid] += t;
    __syncthreads();
  }
  if (tid < nb) bsums[tid] = s[tid] - v;  // exclusive
}
__global__ __launch_bounds__(1024) void k_scan3(int* __restrict__ offs,
                                                const int* __restrict__ bsums, int n, int total) {
  int gid = blockIdx.x * 1024 + threadIdx.x;
  if (gid < n) offs[gid] += bsums[blockIdx.x];
  if (gid == 0) offs[n] = total;
}

// ------------- scatter edge srcs into (dst,type)-sorted order -------------
__global__ void k_scatter(const int* __restrict__ src_dst, const int* __restrict__ et,
                          int* __restrict__ cur, int* __restrict__ srcs, int E) {
  int i = blockIdx.x * 256 + threadIdx.x;
  if (i >= E) return;
  int dst = src_dst[E + i];
  int r = et[i];
  int pos = atomicAdd(&cur[dst * 8 + r], 1);
  srcs[pos] = src_dst[i];
}

// ------------- weight prep: Wt[n][k] = bf16(concat(rel_W, root_W)[k][n]), zero-pad n ----
__global__ void k_prepw(const float* __restrict__ rel,
                        const float* __restrict__ root,
                        unsigned short* __restrict__ Wt, int dout, int doutp) {
  int i = blockIdx.x * 256 + threadIdx.x;
  int tot = doutp * KTOT;
  if (i >= tot) return;
  int n = i / KTOT;
  int k = i - n * KTOT;
  unsigned short v = 0;
  if (n < dout)
    v = f2bf((k < 1024) ? rel[(size_t)k * dout + n] : root[(size_t)(k - 1024) * dout + n]);
  Wt[i] = v;
}

// ------------- per-dst mean aggregation: y[local][11*128] bf16 -------------
// wave per dst node; lane covers dims {2*lane, 2*lane+1}
__global__ __launch_bounds__(256) void k_aggregate(const unsigned int* __restrict__ xin,  // [N][64] bf16-pairs
                                                   unsigned int* __restrict__ yout,      // [mc][704]
                                                   const int* __restrict__ offs,
                                                   const int* __restrict__ srcs,
                                                   const int* __restrict__ node_type,
                                                   int m0, int mc) {
  int wl = blockIdx.x * 4 + (threadIdx.x >> 6);
  if (wl >= mc) return;
  int w = m0 + wl;                       // global node id
  int lane = threadIdx.x & 63;
  unsigned int* yrow = yout + (size_t)wl * 704;
  int base = w * 8;
#pragma unroll 1
  for (int r = 0; r < 8; ++r) {
    int s = offs[base + r], e = offs[base + r + 1];
    float a0 = 0.f, a1 = 0.f;
    for (int j = s; j < e; ++j) {
      int src = srcs[j];  // same for all lanes -> broadcast
      unsigned int u = xin[(size_t)src * 64 + lane];
      a0 += __uint_as_float(u << 16);
      a1 += __uint_as_float(u & 0xffff0000u);
    }
    int c = e - s;
    float sc = (c > 0) ? 1.0f / (float)c : 0.0f;
    yrow[r * 64 + lane] = pack2(a0 * sc, a1 * sc);
  }
  // self slots for the per-node-type root transform
  unsigned int uself = xin[(size_t)w * 64 + lane];
  int nt = node_type[w];
#pragma unroll
  for (int t = 0; t < 3; ++t) yrow[(8 + t) * 64 + lane] = (nt == t) ? uself : 0u;
}

// ------------- MFMA bf16 GEMM: out[M][dout] = Y[M][1408] @ Wt^T + bias(nt) -------------
// mode 1: ReLU -> bf16 outH (layer 1) ; mode 2: f32 outF (layer 2 logits)
__global__ __launch_bounds__(256) void k_gemm(const unsigned short* __restrict__ Y,
                                              const unsigned short* __restrict__ Wt,  // [doutp][1408]
                                              const int* __restrict__ node_type,      // offset by m0
                                              const float* __restrict__ bias,         // [3][dout] f32
                                              unsigned short* __restrict__ outH,
                                              float* __restrict__ outF,
                                              int M, int dout, int mode) {
  __shared__ unsigned short Al[128 * LDA];
  __shared__ unsigned short Bl[128 * LDA];
  int tid = threadIdx.x;
  int m0 = blockIdx.x * 128;
  int n0 = blockIdx.y * 128;
  int lane = tid & 63;
  int w = tid >> 6;
  int wm = (w >> 1) * 64, wn = (w & 1) * 64;
  int l15 = lane & 15, q = lane >> 4;

  v4f acc[4][4];
#pragma unroll
  for (int i = 0; i < 4; ++i)
#pragma unroll
    for (int j = 0; j < 4; ++j) acc[i][j] = (v4f){0.f, 0.f, 0.f, 0.f};

  int arow = tid >> 2, aseg = tid & 3;

  for (int k0 = 0; k0 < KTOT; k0 += 32) {
    // stage A (128 rows x 32 bf16) and B (128 cols x 32 bf16), 2 rows per thread
#pragma unroll
    for (int rr = 0; rr < 128; rr += 64) {
      int row = arow + rr;
      int gm = m0 + row;
      uint4 av = {0u, 0u, 0u, 0u};
      if (gm < M) av = *(const uint4*)(Y + (size_t)gm * KTOT + k0 + aseg * 8);
      *(uint4*)(Al + row * LDA + aseg * 8) = av;
      uint4 bv = *(const uint4*)(Wt + (size_t)(n0 + row) * KTOT + k0 + aseg * 8);
      *(uint4*)(Bl + row * LDA + aseg * 8) = bv;
    }
    __syncthreads();
    v8s a[4], b[4];
#pragma unroll
    for (int ti = 0; ti < 4; ++ti)
      a[ti] = *(const v8s*)(Al + (wm + ti * 16 + l15) * LDA + q * 8);
#pragma unroll
    for (int tj = 0; tj < 4; ++tj)
      b[tj] = *(const v8s*)(Bl + (wn + tj * 16 + l15) * LDA + q * 8);
#pragma unroll
    for (int ti = 0; ti < 4; ++ti)
#pragma unroll
      for (int tj = 0; tj < 4; ++tj)
        acc[ti][tj] = __builtin_amdgcn_mfma_f32_16x16x32_bf16(a[ti], b[tj], acc[ti][tj], 0, 0, 0);
    __syncthreads();
  }

  // epilogue: D col = lane&15, row = (lane>>4)*4 + reg   [measured m89/m91]
#pragma unroll
  for (int ti = 0; ti < 4; ++ti) {
#pragma unroll
    for (int i = 0; i < 4; ++i) {
      int row = m0 + wm + ti * 16 + q * 4 + i;
      if (row >= M) continue;
      int nt = node_type[row];
      const float* brow = bias + nt * dout;
#pragma unroll
      for (int tj = 0; tj < 4; ++tj) {
        int col = n0 + wn + tj * 16 + l15;
        if (col >= dout) continue;
        float v = acc[ti][tj][i] + brow[col];
        if (mode == 1) {
          v = v > 0.f ? v : 0.f;
          outH[(size_t)row * dout + col] = f2bf(v);
        } else {
          outF[(size_t)row * dout + col] = v;
        }
      }
    }
  }
}

// ------------- row-wise log_softmax over 349 f32 cols, in place -------------
__global__ __launch_bounds__(256) void k_softmax(float* __restrict__ X, int M) {
  int w = blockIdx.x * 4 + (threadIdx.x >> 6);
  if (w >= M) return;
  int lane = threadIdx.x & 63;
  float* row = X + (size_t)w * DOUT2;
  float v[6];
  float mx = -3.0e38f;
#pragma unroll
  for (int i = 0; i < 6; ++i) {
    int c = lane + i * 64;
    v[i] = (c < DOUT2) ? row[c] : -3.0e38f;
    mx = fmaxf(mx, v[i]);
  }
#pragma unroll
  for (int o = 32; o > 0; o >>= 1) mx = fmaxf(mx, __shfl_xor(mx, o));
  float s = 0.f;
#pragma unroll
  for (int i = 0; i < 6; ++i) {
    int c = lane + i * 64;
    if (c < DOUT2) s += __expf(v[i] - mx);
  }
#pragma unroll
  for (int o = 32; o > 0; o >>= 1) s += __shfl_xor(s, o);
  float ls = __logf(s);
#pragma unroll
  for (int i = 0; i < 6; ++i) {
    int c = lane + i * 64;
    if (c < DOUT2) row[c] = v[i] - mx - ls;
  }
}

extern "C" void kernel_launch(void* const* d_in, const int* in_sizes, int n_in,
                              void* d_out, int out_size, void* d_ws, size_t ws_size,
                              hipStream_t stream) {
  const float* x0 = (const float*)d_in[0];
  const float* x1 = (const float*)d_in[1];
  const float* emb2 = (const float*)d_in[2];
  const float* relW1 = (const float*)d_in[3];
  const float* rootW1 = (const float*)d_in[4];
  const float* rootb1 = (const float*)d_in[5];
  const float* relW2 = (const float*)d_in[6];
  const float* rootW2 = (const float*)d_in[7];
  const float* rootb2 = (const float*)d_in[8];
  const int* ei_raw = (const int*)d_in[9];
  const int* et_raw = (const int*)d_in[10];
  const int* nt_raw = (const int*)d_in[11];
  const int* li_raw = (const int*)d_in[12];

  const int E = in_sizes[10];
  const int N = in_sizes[11];
  const int NK = N * 8;

  // workspace carve-up (fixed part ~103 MB)
  char* p = (char*)d_ws;
  auto alloc = [&](size_t bytes) {
    char* r = p;
    p += (bytes + 255) & ~(size_t)255;
    return r;
  };
  unsigned short* xbuf = (unsigned short*)alloc((size_t)N * DH * 2);
  unsigned short* hbuf = (unsigned short*)alloc((size_t)N * DH * 2);
  unsigned short* wt1 = (unsigned short*)alloc((size_t)128 * KTOT * 2);
  unsigned short* wt2 = (unsigned short*)alloc((size_t)DOUT2P * KTOT * 2);
  int* offs = (int*)alloc((size_t)(NK + 1) * 4);
  int* cur = (int*)alloc((size_t)NK * 4);
  int* srcs = (int*)alloc((size_t)E * 4);
  int* bsums = (int*)alloc(4096);
  int* ei32 = (int*)alloc((size_t)2 * E * 4);
  int* et32 = (int*)alloc((size_t)E * 4);
  int* nt32 = (int*)alloc((size_t)N * 4);
  int* li32 = (int*)alloc((size_t)N * 4);
  int* flag = (int*)alloc(256);

  // ych takes the remainder; chunk M adaptively (deterministic per session)
  size_t used = (size_t)(p - (char*)d_ws);
  size_t avail = (ws_size > used) ? (ws_size - used) : 0;
  long long maxRows = (long long)(avail / ((size_t)KTOT * 2));
  int chunk = (int)((maxRows / 128) * 128);
  int Nceil = ((N + 127) / 128) * 128;
  if (chunk > Nceil) chunk = Nceil;
  if (chunk < 128) chunk = 128;  // last resort
  unsigned short* ych = (unsigned short*)p;

  float* outF = (float*)d_out;
  const int nScanBlocks = (NK + 1023) / 1024;

  // 0. normalize integer inputs to int32 (auto-detect int64 vs int32)
  hipMemsetAsync(flag, 0, 4, stream);
  hipMemsetAsync(cur, 0, (size_t)NK * 4, stream);
  k_detect<<<(N / 2 + 255) / 256, 256, 0, stream>>>(nt_raw, flag, N / 2);
  k_cvt<<<(2 * E + 255) / 256, 256, 0, stream>>>(ei_raw, ei32, 2 * E, flag);
  k_cvt<<<(E + 255) / 256, 256, 0, stream>>>(et_raw, et32, E, flag);
  k_cvt<<<(N + 255) / 256, 256, 0, stream>>>(nt_raw, nt32, N, flag);
  k_cvt<<<(N + 255) / 256, 256, 0, stream>>>(li_raw, li32, N, flag);

  // 1. build x (bf16) from f32 inputs
  k_gather<<<(N * 32 + 255) / 256, 256, 0, stream>>>((const float4*)x0, (const float4*)x1,
                                                     (const float4*)emb2, nt32, li32,
                                                     (ushort4*)xbuf, N * 32);
  // 2. counting sort of edges by (dst, type)
  k_count<<<(E + 255) / 256, 256, 0, stream>>>(ei32, et32, cur, E);
  k_scan1<<<nScanBlocks, 1024, 0, stream>>>(cur, offs, bsums, NK);
  k_scan2<<<1, 1024, 0, stream>>>(bsums, nScanBlocks);
  k_scan3<<<nScanBlocks, 1024, 0, stream>>>(offs, bsums, NK, E);
  hipMemcpyAsync(cur, offs, (size_t)NK * 4, hipMemcpyDeviceToDevice, stream);
  k_scatter<<<(E + 255) / 256, 256, 0, stream>>>(ei32, et32, cur, srcs, E);
  // 3. weight prep (transpose + bf16 + pad)
  k_prepw<<<(128 * KTOT + 255) / 256, 256, 0, stream>>>(relW1, rootW1, wt1, 128, 128);
  k_prepw<<<(DOUT2P * KTOT + 255) / 256, 256, 0, stream>>>(relW2, rootW2, wt2, DOUT2, DOUT2P);
  // 4. layer 1 (chunked over M): h = relu(conv1) -> bf16
  for (int m0 = 0; m0 < N; m0 += chunk) {
    int mc = (N - m0 < chunk) ? (N - m0) : chunk;
    k_aggregate<<<(mc + 3) / 4, 256, 0, stream>>>((const unsigned int*)xbuf, (unsigned int*)ych,
                                                  offs, srcs, nt32, m0, mc);
    dim3 g1((mc + 127) / 128, 1);
    k_gemm<<<g1, 256, 0, stream>>>(ych, wt1, nt32 + m0, rootb1, hbuf + (size_t)m0 * DH,
                                   (float*)nullptr, mc, 128, 1);
  }
  // 5. layer 2 (chunked over M): f32 logits straight into d_out
  for (int m0 = 0; m0 < N; m0 += chunk) {
    int mc = (N - m0 < chunk) ? (N - m0) : chunk;
    k_aggregate<<<(mc + 3) / 4, 256, 0, stream>>>((const unsigned int*)hbuf, (unsigned int*)ych,
                                                  offs, srcs, nt32, m0, mc);
    dim3 g2((mc + 127) / 128, DOUT2P / 128);
    k_gemm<<<g2, 256, 0, stream>>>(ych, wt2, nt32 + m0, rootb2, (unsigned short*)nullptr,
                                   outF + (size_t)m0 * DOUT2, mc, DOUT2, 2);
  }
  // 6. log_softmax in place on f32 d_out
  k_softmax<<<(N + 3) / 4, 256, 0, stream>>>(outF, N);
}

// Round 4
// 1355.938 us; speedup vs baseline: 1.1736x; 1.1736x over previous
//
#include <hip/hip_runtime.h>

// ---------------- constants for this problem ----------------
#define DH 128          // d_in = d_hidden = 128
#define KTOT 1408       // 8*128 rel + 3*128 root slots
#define DOUT2 349
#define DOUT2P 384      // padded to 3 x 128 N-tiles

typedef short v8s __attribute__((ext_vector_type(8)));
typedef float v4f __attribute__((ext_vector_type(4)));

__device__ __forceinline__ unsigned short f2bf(float f) {
  unsigned int u = __float_as_uint(f);
  u += 0x7fffu + ((u >> 16) & 1u);
  return (unsigned short)(u >> 16);
}
__device__ __forceinline__ unsigned int pack2(float a, float b) {
  return (unsigned int)f2bf(a) | ((unsigned int)f2bf(b) << 16);
}

// async global->LDS, 16B per lane; LDS dest = wave-uniform base + lane*16
__device__ __forceinline__ void gl2lds16(const unsigned short* g, unsigned short* l) {
  __builtin_amdgcn_global_load_lds((const __attribute__((address_space(1))) unsigned int*)g,
                                   (__attribute__((address_space(3))) unsigned int*)l, 16, 0, 0);
}

// ------------- int64-vs-int32 detect + normalize -------------
__global__ void k_detect(const int* __restrict__ nt_raw, int* __restrict__ flag, int half) {
  int i = blockIdx.x * 256 + threadIdx.x;
  if (i >= half) return;
  if (nt_raw[2 * i + 1] != 0) atomicOr(flag, 1);
}
__global__ void k_cvt(const int* __restrict__ in, int* __restrict__ out, int n,
                      const int* __restrict__ flag) {
  int i = blockIdx.x * 256 + threadIdx.x;
  if (i >= n) return;
  out[i] = (*flag) ? in[i] : in[2 * i];  // int64: little-endian low word
}

// ------------- build x [N][128] bf16 from f32 x0/x1/emb2 -------------
__global__ void k_gather(const float4* __restrict__ x0, const float4* __restrict__ x1,
                         const float4* __restrict__ x2, const int* __restrict__ nt,
                         const int* __restrict__ li, ushort4* __restrict__ xout, int total) {
  int i = blockIdx.x * 256 + threadIdx.x;
  if (i >= total) return;              // total = N*32 (32 float4 per 128-f32 row)
  int node = i >> 5, c = i & 31;
  int t = nt[node];
  int l = li[node];
  const float4* s = (t == 0) ? x0 : (t == 1) ? x1 : x2;
  float4 v = s[(size_t)l * 32 + c];
  ushort4 o;
  o.x = f2bf(v.x); o.y = f2bf(v.y); o.z = f2bf(v.z); o.w = f2bf(v.w);
  xout[i] = o;
}

// ------------- histogram over key = dst*8 + edge_type -------------
__global__ void k_count(const int* __restrict__ src_dst, const int* __restrict__ et,
                        int* __restrict__ cnt, int E) {
  int i = blockIdx.x * 256 + threadIdx.x;
  if (i >= E) return;
  int dst = src_dst[E + i];
  int r = et[i];
  atomicAdd(&cnt[dst * 8 + r], 1);
}

// ------------- 3-phase exclusive scan over n = N*8 -------------
__global__ __launch_bounds__(1024) void k_scan1(const int* __restrict__ cnt,
                                                int* __restrict__ outl,
                                                int* __restrict__ bsums, int n) {
  __shared__ int s[1024];
  int tid = threadIdx.x;
  int gid = blockIdx.x * 1024 + tid;
  int v = (gid < n) ? cnt[gid] : 0;
  s[tid] = v;
  __syncthreads();
  for (int o = 1; o < 1024; o <<= 1) {
    int t = (tid >= o) ? s[tid - o] : 0;
    __syncthreads();
    s[tid] += t;
    __syncthreads();
  }
  if (gid < n) outl[gid] = s[tid] - v;  // exclusive, block-local
  if (tid == 1023) bsums[blockIdx.x] = s[1023];
}
__global__ __launch_bounds__(1024) void k_scan2(int* __restrict__ bsums, int nb) {
  __shared__ int s[1024];
  int tid = threadIdx.x;
  int v = (tid < nb) ? bsums[tid] : 0;
  s[tid] = v;
  __syncthreads();
  for (int o = 1; o < 1024; o <<= 1) {
    int t = (tid >= o) ? s[tid - o] : 0;
    __syncthreads();
    s[tid] += t;
    __syncthreads();
  }
  if (tid < nb) bsums[tid] = s[tid] - v;  // exclusive
}
__global__ __launch_bounds__(1024) void k_scan3(int* __restrict__ offs,
                                                const int* __restrict__ bsums, int n, int total) {
  int gid = blockIdx.x * 1024 + threadIdx.x;
  if (gid < n) offs[gid] += bsums[blockIdx.x];
  if (gid == 0) offs[n] = total;
}

// ------------- scatter edge srcs into (dst,type)-sorted order -------------
__global__ void k_scatter(const int* __restrict__ src_dst, const int* __restrict__ et,
                          int* __restrict__ cur, int* __restrict__ srcs, int E) {
  int i = blockIdx.x * 256 + threadIdx.x;
  if (i >= E) return;
  int dst = src_dst[E + i];
  int r = et[i];
  int pos = atomicAdd(&cur[dst * 8 + r], 1);
  srcs[pos] = src_dst[i];
}

// ------------- weight prep: Wt[n][k] = bf16(concat(rel_W, root_W)[k][n]), zero-pad n ----
__global__ void k_prepw(const float* __restrict__ rel,
                        const float* __restrict__ root,
                        unsigned short* __restrict__ Wt, int dout, int doutp) {
  int i = blockIdx.x * 256 + threadIdx.x;
  int tot = doutp * KTOT;
  if (i >= tot) return;
  int n = i / KTOT;
  int k = i - n * KTOT;
  unsigned short v = 0;
  if (n < dout)
    v = f2bf((k < 1024) ? rel[(size_t)k * dout + n] : root[(size_t)(k - 1024) * dout + n]);
  Wt[i] = v;
}

// ------------- per-dst mean aggregation: y[local][11*128] bf16 -------------
// TWO waves per node (4 rels each) for 2x wave parallelism; edge loop
// unrolled by 2 for load-latency ILP. Lane covers dims {2*lane, 2*lane+1}.
__global__ __launch_bounds__(256) void k_aggregate(const unsigned int* __restrict__ xin,  // [N][64] bf16-pairs
                                                   unsigned int* __restrict__ yout,      // [mc][704]
                                                   const int* __restrict__ offs,
                                                   const int* __restrict__ srcs,
                                                   const int* __restrict__ node_type,
                                                   int m0, int mc) {
  int wid = blockIdx.x * 4 + (threadIdx.x >> 6);
  int wl = wid >> 1;       // local node
  int h = wid & 1;         // half: rels h*4 .. h*4+3
  if (wl >= mc) return;
  int w = m0 + wl;         // global node id
  int lane = threadIdx.x & 63;
  unsigned int* yrow = yout + (size_t)wl * 704;
  int base = w * 8 + h * 4;
#pragma unroll
  for (int r = 0; r < 4; ++r) {
    int s = offs[base + r], e = offs[base + r + 1];
    float a0 = 0.f, a1 = 0.f, b0 = 0.f, b1 = 0.f;
    int j = s;
    for (; j + 2 <= e; j += 2) {
      int s1 = srcs[j], s2 = srcs[j + 1];
      unsigned int u1 = xin[(size_t)s1 * 64 + lane];
      unsigned int u2 = xin[(size_t)s2 * 64 + lane];
      a0 += __uint_as_float(u1 << 16);
      a1 += __uint_as_float(u1 & 0xffff0000u);
      b0 += __uint_as_float(u2 << 16);
      b1 += __uint_as_float(u2 & 0xffff0000u);
    }
    if (j < e) {
      int s1 = srcs[j];
      unsigned int u1 = xin[(size_t)s1 * 64 + lane];
      a0 += __uint_as_float(u1 << 16);
      a1 += __uint_as_float(u1 & 0xffff0000u);
    }
    int c = e - s;
    float sc = (c > 0) ? 1.0f / (float)c : 0.0f;
    yrow[(h * 4 + r) * 64 + lane] = pack2((a0 + b0) * sc, (a1 + b1) * sc);
  }
  if (h == 0) {
    // self slots for the per-node-type root transform
    unsigned int uself = xin[(size_t)w * 64 + lane];
    int nt = node_type[w];
#pragma unroll
    for (int t = 0; t < 3; ++t) yrow[(8 + t) * 64 + lane] = (nt == t) ? uself : 0u;
  }
}

// ------------- MFMA bf16 GEMM (m97 structure): out = Y[M][1408] @ Wt^T + bias(nt) ------
// grid.x = n-tiles (fastest -> A-tile L2 reuse), grid.y = m-tiles.
// Staging via global_load_lds width=16 into unpadded [128][32] LDS tiles.
// Y must be readable for gridDim.y*128 rows (caller guarantees; extra rows' results
// are discarded via the row<M epilogue check).
// mode 1: ReLU -> bf16 outH (layer 1) ; mode 2: f32 outF (layer 2 logits)
__global__ __launch_bounds__(256) void k_gemm(const unsigned short* __restrict__ Y,
                                              const unsigned short* __restrict__ Wt,  // [doutp][1408]
                                              const int* __restrict__ node_type,      // offset by m0
                                              const float* __restrict__ bias,         // [3][dout] f32
                                              unsigned short* __restrict__ outH,
                                              float* __restrict__ outF,
                                              int M, int dout, int mode) {
  __shared__ unsigned short Al[128 * 32];
  __shared__ unsigned short Bl[128 * 32];
  int tid = threadIdx.x;
  int n0 = blockIdx.x * 128;
  int m0 = blockIdx.y * 128;
  int lane = tid & 63;
  int w = tid >> 6;
  int wm = (w >> 1) * 64, wn = (w & 1) * 64;
  int l15 = lane & 15, q = lane >> 4;

  v4f acc[4][4];
#pragma unroll
  for (int i = 0; i < 4; ++i)
#pragma unroll
    for (int j = 0; j < 4; ++j) acc[i][j] = (v4f){0.f, 0.f, 0.f, 0.f};

  // global_load_lds coords: call c in {0,1} per wave covers rows 16*(2w+c)..+15.
  // lane l -> row 16*(2w+c) + (l>>2), k-seg 8*(l&3); LDS slot = base + l*16B.
  int rbase = 16 * (2 * w);
  const unsigned short* Ag0 = Y + (size_t)(m0 + rbase + (lane >> 2)) * KTOT + 8 * (lane & 3);
  const unsigned short* Bg0 = Wt + (size_t)(n0 + rbase + (lane >> 2)) * KTOT + 8 * (lane & 3);
  unsigned short* Asl0 = Al + (2 * w) * 512;        // 512 shorts = 1 KB per wave-call
  unsigned short* Bsl0 = Bl + (2 * w) * 512;

  for (int k0 = 0; k0 < KTOT; k0 += 32) {
    gl2lds16(Ag0 + k0, Asl0);
    gl2lds16(Ag0 + (size_t)16 * KTOT + k0, Asl0 + 512);
    gl2lds16(Bg0 + k0, Bsl0);
    gl2lds16(Bg0 + (size_t)16 * KTOT + k0, Bsl0 + 512);
    __syncthreads();   // drains vmcnt -> LDS tiles complete
    v8s a[4], b[4];
#pragma unroll
    for (int ti = 0; ti < 4; ++ti)
      a[ti] = *(const v8s*)(Al + (wm + ti * 16 + l15) * 32 + q * 8);
#pragma unroll
    for (int tj = 0; tj < 4; ++tj)
      b[tj] = *(const v8s*)(Bl + (wn + tj * 16 + l15) * 32 + q * 8);
#pragma unroll
    for (int ti = 0; ti < 4; ++ti)
#pragma unroll
      for (int tj = 0; tj < 4; ++tj)
        acc[ti][tj] = __builtin_amdgcn_mfma_f32_16x16x32_bf16(a[ti], b[tj], acc[ti][tj], 0, 0, 0);
    __syncthreads();   // protect LDS from next iteration's overwrite
  }

  // epilogue: D col = lane&15, row = (lane>>4)*4 + reg   [measured m89/m91]
#pragma unroll
  for (int ti = 0; ti < 4; ++ti) {
#pragma unroll
    for (int i = 0; i < 4; ++i) {
      int row = m0 + wm + ti * 16 + q * 4 + i;
      if (row >= M) continue;
      int nt = node_type[row];
      const float* brow = bias + nt * dout;
#pragma unroll
      for (int tj = 0; tj < 4; ++tj) {
        int col = n0 + wn + tj * 16 + l15;
        if (col >= dout) continue;
        float v = acc[ti][tj][i] + brow[col];
        if (mode == 1) {
          v = v > 0.f ? v : 0.f;
          outH[(size_t)row * dout + col] = f2bf(v);
        } else {
          outF[(size_t)row * dout + col] = v;
        }
      }
    }
  }
}

// ------------- row-wise log_softmax over 349 f32 cols, in place -------------
__global__ __launch_bounds__(256) void k_softmax(float* __restrict__ X, int M) {
  int w = blockIdx.x * 4 + (threadIdx.x >> 6);
  if (w >= M) return;
  int lane = threadIdx.x & 63;
  float* row = X + (size_t)w * DOUT2;
  float v[6];
  float mx = -3.0e38f;
#pragma unroll
  for (int i = 0; i < 6; ++i) {
    int c = lane + i * 64;
    v[i] = (c < DOUT2) ? row[c] : -3.0e38f;
    mx = fmaxf(mx, v[i]);
  }
#pragma unroll
  for (int o = 32; o > 0; o >>= 1) mx = fmaxf(mx, __shfl_xor(mx, o));
  float s = 0.f;
#pragma unroll
  for (int i = 0; i < 6; ++i) {
    int c = lane + i * 64;
    if (c < DOUT2) s += __expf(v[i] - mx);
  }
#pragma unroll
  for (int o = 32; o > 0; o >>= 1) s += __shfl_xor(s, o);
  float ls = __logf(s);
#pragma unroll
  for (int i = 0; i < 6; ++i) {
    int c = lane + i * 64;
    if (c < DOUT2) row[c] = v[i] - mx - ls;
  }
}

extern "C" void kernel_launch(void* const* d_in, const int* in_sizes, int n_in,
                              void* d_out, int out_size, void* d_ws, size_t ws_size,
                              hipStream_t stream) {
  const float* x0 = (const float*)d_in[0];
  const float* x1 = (const float*)d_in[1];
  const float* emb2 = (const float*)d_in[2];
  const float* relW1 = (const float*)d_in[3];
  const float* rootW1 = (const float*)d_in[4];
  const float* rootb1 = (const float*)d_in[5];
  const float* relW2 = (const float*)d_in[6];
  const float* rootW2 = (const float*)d_in[7];
  const float* rootb2 = (const float*)d_in[8];
  const int* ei_raw = (const int*)d_in[9];
  const int* et_raw = (const int*)d_in[10];
  const int* nt_raw = (const int*)d_in[11];
  const int* li_raw = (const int*)d_in[12];

  const int E = in_sizes[10];
  const int N = in_sizes[11];
  const int NK = N * 8;

  // workspace carve-up (fixed part ~103 MB)
  char* p = (char*)d_ws;
  auto alloc = [&](size_t bytes) {
    char* r = p;
    p += (bytes + 255) & ~(size_t)255;
    return r;
  };
  unsigned short* xbuf = (unsigned short*)alloc((size_t)N * DH * 2);
  unsigned short* hbuf = (unsigned short*)alloc((size_t)N * DH * 2);
  unsigned short* wt1 = (unsigned short*)alloc((size_t)128 * KTOT * 2);
  unsigned short* wt2 = (unsigned short*)alloc((size_t)DOUT2P * KTOT * 2);
  int* offs = (int*)alloc((size_t)(NK + 1) * 4);
  int* cur = (int*)alloc((size_t)NK * 4);
  int* srcs = (int*)alloc((size_t)E * 4);
  int* bsums = (int*)alloc(4096);
  int* ei32 = (int*)alloc((size_t)2 * E * 4);
  int* et32 = (int*)alloc((size_t)E * 4);
  int* nt32 = (int*)alloc((size_t)N * 4);
  int* li32 = (int*)alloc((size_t)N * 4);
  int* flag = (int*)alloc(256);

  // ych takes the remainder; chunk M adaptively (deterministic per session)
  size_t used = (size_t)(p - (char*)d_ws);
  size_t avail = (ws_size > used) ? (ws_size - used) : 0;
  long long maxRows = (long long)(avail / ((size_t)KTOT * 2));
  int chunk = (int)((maxRows / 128) * 128);
  int Nceil = ((N + 127) / 128) * 128;
  if (chunk > Nceil) chunk = Nceil;
  if (chunk < 128) chunk = 128;  // last resort
  unsigned short* ych = (unsigned short*)p;

  float* outF = (float*)d_out;
  const int nScanBlocks = (NK + 1023) / 1024;

  // 0. normalize integer inputs to int32 (auto-detect int64 vs int32)
  hipMemsetAsync(flag, 0, 4, stream);
  hipMemsetAsync(cur, 0, (size_t)NK * 4, stream);
  k_detect<<<(N / 2 + 255) / 256, 256, 0, stream>>>(nt_raw, flag, N / 2);
  k_cvt<<<(2 * E + 255) / 256, 256, 0, stream>>>(ei_raw, ei32, 2 * E, flag);
  k_cvt<<<(E + 255) / 256, 256, 0, stream>>>(et_raw, et32, E, flag);
  k_cvt<<<(N + 255) / 256, 256, 0, stream>>>(nt_raw, nt32, N, flag);
  k_cvt<<<(N + 255) / 256, 256, 0, stream>>>(li_raw, li32, N, flag);

  // 1. build x (bf16) from f32 inputs
  k_gather<<<(N * 32 + 255) / 256, 256, 0, stream>>>((const float4*)x0, (const float4*)x1,
                                                     (const float4*)emb2, nt32, li32,
                                                     (ushort4*)xbuf, N * 32);
  // 2. counting sort of edges by (dst, type)
  k_count<<<(E + 255) / 256, 256, 0, stream>>>(ei32, et32, cur, E);
  k_scan1<<<nScanBlocks, 1024, 0, stream>>>(cur, offs, bsums, NK);
  k_scan2<<<1, 1024, 0, stream>>>(bsums, nScanBlocks);
  k_scan3<<<nScanBlocks, 1024, 0, stream>>>(offs, bsums, NK, E);
  hipMemcpyAsync(cur, offs, (size_t)NK * 4, hipMemcpyDeviceToDevice, stream);
  k_scatter<<<(E + 255) / 256, 256, 0, stream>>>(ei32, et32, cur, srcs, E);
  // 3. weight prep (transpose + bf16 + pad)
  k_prepw<<<(128 * KTOT + 255) / 256, 256, 0, stream>>>(relW1, rootW1, wt1, 128, 128);
  k_prepw<<<(DOUT2P * KTOT + 255) / 256, 256, 0, stream>>>(relW2, rootW2, wt2, DOUT2, DOUT2P);
  // 4. layer 1 (chunked over M): h = relu(conv1) -> bf16
  for (int m0 = 0; m0 < N; m0 += chunk) {
    int mc = (N - m0 < chunk) ? (N - m0) : chunk;
    k_aggregate<<<(2 * mc + 3) / 4, 256, 0, stream>>>((const unsigned int*)xbuf,
                                                      (unsigned int*)ych, offs, srcs, nt32, m0, mc);
    dim3 g1(1, (mc + 127) / 128);
    k_gemm<<<g1, 256, 0, stream>>>(ych, wt1, nt32 + m0, rootb1, hbuf + (size_t)m0 * DH,
                                   (float*)nullptr, mc, 128, 1);
  }
  // 5. layer 2 (chunked over M): f32 logits straight into d_out (n fastest for A reuse)
  for (int m0 = 0; m0 < N; m0 += chunk) {
    int mc = (N - m0 < chunk) ? (N - m0) : chunk;
    k_aggregate<<<(2 * mc + 3) / 4, 256, 0, stream>>>((const unsigned int*)hbuf,
                                                      (unsigned int*)ych, offs, srcs, nt32, m0, mc);
    dim3 g2(DOUT2P / 128, (mc + 127) / 128);
    k_gemm<<<g2, 256, 0, stream>>>(ych, wt2, nt32 + m0, rootb2, (unsigned short*)nullptr,
                                   outF + (size_t)m0 * DOUT2, mc, DOUT2, 2);
  }
  // 6. log_softmax in place on f32 d_out
  k_softmax<<<(N + 3) / 4, 256, 0, stream>>>(outF, N);
}